// Round 6
// baseline (710.370 us; speedup 1.0000x reference)
//
#include <hip/hip_runtime.h>
#include <cstdint>
#include <cstddef>

typedef __bf16 bf16_t;
typedef __attribute__((ext_vector_type(8))) __bf16 bf16x8;
typedef __attribute__((ext_vector_type(4))) __bf16 bf16x4;
typedef __attribute__((ext_vector_type(4))) float floatx4;

#define NB 32
#define NW 168
#define NM 2048
#define NHID 128
#define NBW 5376  // NB*NW

#define GLOAD_LDS16(g, l)                                          \
  __builtin_amdgcn_global_load_lds(                                \
      (const __attribute__((address_space(1))) void*)(g),          \
      (__attribute__((address_space(3))) void*)(l), 16, 0, 0)

// One-shot prep: blocks [0,2688): x -> Xb [(b,w)][m] bf16 + XT [m][(b,w)] bf16;
// [2688,3200): L -> Lb bf16; [3200,3207): W1 -> W1p [7][128][192] bf16, k>=168 zeroed.
__global__ void prep_all(const float* __restrict__ x, bf16_t* __restrict__ Xb,
                         bf16_t* __restrict__ XT, const float* __restrict__ L,
                         bf16_t* __restrict__ Lb, const float* __restrict__ W1,
                         bf16_t* __restrict__ W1p) {
  __shared__ float tile[64][65];
  int bid = blockIdx.x;
  int t = threadIdx.x;
  if (bid < 2688) {
    const int C = NM;
    int r0 = (bid >> 5) * 64, c0 = (bid & 31) * 64;
    int tr = t >> 4, tc4 = (t & 15) * 4;
#pragma unroll
    for (int p = 0; p < 4; ++p) {
      int row = p * 16 + tr;
      float4 v = *(const float4*)(x + (size_t)(r0 + row) * C + c0 + tc4);
      tile[row][tc4 + 0] = v.x;
      tile[row][tc4 + 1] = v.y;
      tile[row][tc4 + 2] = v.z;
      tile[row][tc4 + 3] = v.w;
      bf16x4 o = {(bf16_t)v.x, (bf16_t)v.y, (bf16_t)v.z, (bf16_t)v.w};
      *(bf16x4*)(Xb + (size_t)(r0 + row) * C + c0 + tc4) = o;
    }
    __syncthreads();
#pragma unroll
    for (int p = 0; p < 4; ++p) {
      int c = p * 16 + tr;
      bf16x4 o = {(bf16_t)tile[tc4 + 0][c], (bf16_t)tile[tc4 + 1][c],
                  (bf16_t)tile[tc4 + 2][c], (bf16_t)tile[tc4 + 3][c]};
      *(bf16x4*)(XT + (size_t)(c0 + c) * NBW + r0 + tc4) = o;
    }
  } else if (bid < 3200) {
    int i = (bid - 2688) * 256 + t;
    const int n4 = NM * NM / 4;
    const int stride = 512 * 256;
    for (; i < n4; i += stride) {
      float4 v = ((const float4*)L)[i];
      bf16x4 o = {(bf16_t)v.x, (bf16_t)v.y, (bf16_t)v.z, (bf16_t)v.w};
      ((bf16x4*)Lb)[i] = o;
    }
  } else {
    int hop = bid - 3200;
    const float* src = W1 + (size_t)hop * NHID * NW;
    bf16_t* dst = W1p + (size_t)hop * NHID * 192;
    for (int c = t; c < 3072; c += 256) {
      int h = c / 24, kc = c % 24;
      bf16x8 o;
      if (kc < 21) {
        const float* s = src + (size_t)h * NW + kc * 8;
#pragma unroll
        for (int j = 0; j < 8; ++j) o[j] = (bf16_t)s[j];
      } else {
#pragma unroll
        for (int j = 0; j < 8; ++j) o[j] = (bf16_t)0.0f;
      }
      *(bf16x8*)(dst + (size_t)h * 192 + kc * 8) = o;
    }
  }
}

// Main NT GEMM, BK=64 double-width K-step (half the barriers of BK=32):
// Tt_out[(bw)][m] = sum_k A[(bw)][k] * Lb[m][k];  writes XTout (transposed,
// bf16x4-contig) always, Tt (row-major) if write_c. 672 blocks.
// LDS 128x64 per operand, XOR swizzle c' = c ^ (row&7) -> 2-way reads (free).
__global__ void gemm_bk64(const bf16_t* __restrict__ A, const bf16_t* __restrict__ Lb,
                          bf16_t* __restrict__ Tt, bf16_t* __restrict__ XTout, int write_c) {
  __shared__ bf16_t As[128 * 64];
  __shared__ bf16_t Bs[128 * 64];
  int tid = threadIdx.x, bid = blockIdx.x;
  int m0 = (bid >> 4) * 128, n0 = (bid & 15) * 128;
  int lane = tid & 63, wv = tid >> 6;
  int wm = wv >> 1, wn = wv & 1;
  int quad = lane >> 4, l15 = lane & 15;

  // staging: 1024 chunks/buffer; wave wv covers [wv*256, wv*256+256) in 4 issues
  const bf16_t* apj[4];
  const bf16_t* bpj[4];
  bf16_t* adj[4];
  bf16_t* bdj[4];
#pragma unroll
  for (int j = 0; j < 4; ++j) {
    int p = wv * 256 + j * 64 + lane;
    int r = p >> 3, c = (p & 7) ^ (r & 7);
    apj[j] = A + (size_t)(m0 + r) * NM + c * 8;
    bpj[j] = Lb + (size_t)(n0 + r) * NM + c * 8;
    adj[j] = As + (size_t)(wv * 256 + j * 64) * 8;
    bdj[j] = Bs + (size_t)(wv * 256 + j * 64) * 8;
  }
  int swz = l15 & 7;

  floatx4 zero4 = {0.f, 0.f, 0.f, 0.f};
  floatx4 acc[4][4];
#pragma unroll
  for (int mi = 0; mi < 4; ++mi)
#pragma unroll
    for (int ni = 0; ni < 4; ++ni) acc[mi][ni] = zero4;

  for (int kb = 0; kb < 2048; kb += 64) {
#pragma unroll
    for (int j = 0; j < 4; ++j) GLOAD_LDS16(apj[j] + kb, adj[j]);
#pragma unroll
    for (int j = 0; j < 4; ++j) GLOAD_LDS16(bpj[j] + kb, bdj[j]);
    __syncthreads();
#pragma unroll
    for (int h = 0; h < 2; ++h) {
      bf16x8 af[4], bf[4];
#pragma unroll
      for (int mi = 0; mi < 4; ++mi)
        af[mi] = *(const bf16x8*)(As + (wm * 64 + mi * 16 + l15) * 64 + (((h * 4 + quad) ^ swz) & 7) * 8);
#pragma unroll
      for (int ni = 0; ni < 4; ++ni)
        bf[ni] = *(const bf16x8*)(Bs + (wn * 64 + ni * 16 + l15) * 64 + (((h * 4 + quad) ^ swz) & 7) * 8);
#pragma unroll
      for (int mi = 0; mi < 4; ++mi)
#pragma unroll
        for (int ni = 0; ni < 4; ++ni)
          acc[mi][ni] = __builtin_amdgcn_mfma_f32_16x16x32_bf16(af[mi], bf[ni], acc[mi][ni], 0, 0, 0);
    }
    __syncthreads();
  }
#pragma unroll
  for (int mi = 0; mi < 4; ++mi) {
#pragma unroll
    for (int ni = 0; ni < 4; ++ni) {
      int col = n0 + wn * 64 + ni * 16 + l15;
      int rowb = m0 + wm * 64 + mi * 16 + quad * 4;
      bf16x4 tv;
#pragma unroll
      for (int r = 0; r < 4; ++r) tv[r] = (bf16_t)acc[mi][ni][r];
      *(bf16x4*)(XTout + (size_t)col * NBW + rowb) = tv;
      if (write_c) {
#pragma unroll
        for (int r = 0; r < 4; ++r) Tt[(size_t)(rowb + r) * NM + col] = tv[r];
      }
    }
  }
}

// Hop-6 projection: Zt[(b*128+h)][k] = sum_w W1p6[h][w] * XT5[k][b*168+w].
// 512 blocks (b*16 + k-tile); all operands read direct from global; no LDS.
__global__ void zproj(const bf16_t* __restrict__ XT5, const bf16_t* __restrict__ W1p,
                      bf16_t* __restrict__ Zt) {
  int bid = blockIdx.x;
  int b = bid >> 4, n0 = (bid & 15) * 128;
  const bf16_t* W6 = W1p + (size_t)6 * NHID * 192;
  int tid = threadIdx.x;
  int lane = tid & 63, wv = tid >> 6;
  int wm = wv >> 1, wn = wv & 1;
  int quad = lane >> 4, l15 = lane & 15;
  const bf16_t* arow[4];
  const bf16_t* brow[4];
#pragma unroll
  for (int mi = 0; mi < 4; ++mi)
    arow[mi] = W6 + (size_t)(wm * 64 + mi * 16 + l15) * 192 + quad * 8;
#pragma unroll
  for (int ni = 0; ni < 4; ++ni)
    brow[ni] = XT5 + (size_t)(n0 + wn * 64 + ni * 16 + l15) * NBW + b * NW + quad * 8;

  floatx4 zero4 = {0.f, 0.f, 0.f, 0.f};
  floatx4 acc[4][4];
#pragma unroll
  for (int mi = 0; mi < 4; ++mi)
#pragma unroll
    for (int ni = 0; ni < 4; ++ni) acc[mi][ni] = zero4;

#pragma unroll
  for (int kb = 0; kb < 192; kb += 32) {
    bf16x8 af[4], bf[4];
#pragma unroll
    for (int mi = 0; mi < 4; ++mi) af[mi] = *(const bf16x8*)(arow[mi] + kb);
#pragma unroll
    for (int ni = 0; ni < 4; ++ni) bf[ni] = *(const bf16x8*)(brow[ni] + kb);  // w>=168: A pad=0
#pragma unroll
    for (int mi = 0; mi < 4; ++mi)
#pragma unroll
      for (int ni = 0; ni < 4; ++ni)
        acc[mi][ni] = __builtin_amdgcn_mfma_f32_16x16x32_bf16(af[mi], bf[ni], acc[mi][ni], 0, 0, 0);
  }
#pragma unroll
  for (int mi = 0; mi < 4; ++mi) {
#pragma unroll
    for (int ni = 0; ni < 4; ++ni) {
      int col = n0 + wn * 64 + ni * 16 + l15;
      int rowb = b * 128 + wm * 64 + mi * 16 + quad * 4;
#pragma unroll
      for (int r = 0; r < 4; ++r)
        Zt[(size_t)(rowb + r) * NM + col] = (bf16_t)acc[mi][ni][r];
    }
  }
}

// Hop-6 GEMM + fused score: H[m][(b,h)] = sum_k Lb[m][k]*Zt[(b*128+h)][k];
// epilogue: out[b*NM+m] += sum_h relu(H+b1_6)*W2_6 + b2_6. 512 blocks (mt*32+b).
__global__ void gemm_h6(const bf16_t* __restrict__ Lb, const bf16_t* __restrict__ Zt,
                        const float* __restrict__ b1, const float* __restrict__ W2,
                        const float* __restrict__ b2, float* __restrict__ out) {
  __shared__ bf16_t As[128 * 64];
  __shared__ bf16_t Bs[128 * 64];
  __shared__ float sred[4][64];
  int tid = threadIdx.x, bid = blockIdx.x;
  int m0 = (bid >> 5) * 128, b = bid & 31;
  int n0 = b * 128;
  int lane = tid & 63, wv = tid >> 6;
  int wm = wv >> 1, wn = wv & 1;
  int quad = lane >> 4, l15 = lane & 15;

  const bf16_t* apj[4];
  const bf16_t* bpj[4];
  bf16_t* adj[4];
  bf16_t* bdj[4];
#pragma unroll
  for (int j = 0; j < 4; ++j) {
    int p = wv * 256 + j * 64 + lane;
    int r = p >> 3, c = (p & 7) ^ (r & 7);
    apj[j] = Lb + (size_t)(m0 + r) * NM + c * 8;
    bpj[j] = Zt + (size_t)(n0 + r) * NM + c * 8;
    adj[j] = As + (size_t)(wv * 256 + j * 64) * 8;
    bdj[j] = Bs + (size_t)(wv * 256 + j * 64) * 8;
  }
  int swz = l15 & 7;

  floatx4 zero4 = {0.f, 0.f, 0.f, 0.f};
  floatx4 acc[4][4];
#pragma unroll
  for (int mi = 0; mi < 4; ++mi)
#pragma unroll
    for (int ni = 0; ni < 4; ++ni) acc[mi][ni] = zero4;

  for (int kb = 0; kb < 2048; kb += 64) {
#pragma unroll
    for (int j = 0; j < 4; ++j) GLOAD_LDS16(apj[j] + kb, adj[j]);
#pragma unroll
    for (int j = 0; j < 4; ++j) GLOAD_LDS16(bpj[j] + kb, bdj[j]);
    __syncthreads();
#pragma unroll
    for (int h = 0; h < 2; ++h) {
      bf16x8 af[4], bf[4];
#pragma unroll
      for (int mi = 0; mi < 4; ++mi)
        af[mi] = *(const bf16x8*)(As + (wm * 64 + mi * 16 + l15) * 64 + (((h * 4 + quad) ^ swz) & 7) * 8);
#pragma unroll
      for (int ni = 0; ni < 4; ++ni)
        bf[ni] = *(const bf16x8*)(Bs + (wn * 64 + ni * 16 + l15) * 64 + (((h * 4 + quad) ^ swz) & 7) * 8);
#pragma unroll
      for (int mi = 0; mi < 4; ++mi)
#pragma unroll
        for (int ni = 0; ni < 4; ++ni)
          acc[mi][ni] = __builtin_amdgcn_mfma_f32_16x16x32_bf16(af[mi], bf[ni], acc[mi][ni], 0, 0, 0);
    }
    __syncthreads();
  }

  // fused epilogue: per local row, sum_h relu(acc + b1_6[h]) * W2_6[h]
  const float* b1h = b1 + 6 * NHID;
  const float* w2h = W2 + 6 * NHID;
  float part[4][4];
#pragma unroll
  for (int mi = 0; mi < 4; ++mi)
#pragma unroll
    for (int r = 0; r < 4; ++r) part[mi][r] = 0.f;
#pragma unroll
  for (int ni = 0; ni < 4; ++ni) {
    int col = wn * 64 + ni * 16 + l15;  // = h
    float b1v = b1h[col];
    float w2v = w2h[col];
#pragma unroll
    for (int mi = 0; mi < 4; ++mi)
#pragma unroll
      for (int r = 0; r < 4; ++r) {
        float hh = acc[mi][ni][r] + b1v;
        hh = hh > 0.f ? hh : 0.f;
        part[mi][r] += hh * w2v;
      }
  }
#pragma unroll
  for (int off = 1; off < 16; off <<= 1)
#pragma unroll
    for (int mi = 0; mi < 4; ++mi)
#pragma unroll
      for (int r = 0; r < 4; ++r) part[mi][r] += __shfl_xor(part[mi][r], off);
  if (l15 == 0) {
#pragma unroll
    for (int mi = 0; mi < 4; ++mi)
#pragma unroll
      for (int r = 0; r < 4; ++r) sred[wv][mi * 16 + quad * 4 + r] = part[mi][r];
  }
  __syncthreads();
  if (tid < 128) {
    int half = tid >> 6;
    int lr = tid & 63;
    float v = sred[half * 2][lr] + sred[half * 2 + 1][lr] + b2[6];
    out[(size_t)b * NM + m0 + half * 64 + lr] += v;  // unique (b,m) per dispatch
  }
}

// Per-hop MLP + score (hops 0..5). Rows r = m*32+b (128/block); A from XT,
// W1 staged from zero-padded W1p into LDS [kc][h^swz] (no predication needed).
__global__ void mlp_score(const bf16_t* __restrict__ XT, const bf16_t* __restrict__ W1p,
                          const float* __restrict__ b1, const float* __restrict__ W2,
                          const float* __restrict__ b2, float* __restrict__ out,
                          int hop, int accumulate) {
  __shared__ bf16_t Bs[24 * 128 * 8];  // 48 KB
  __shared__ float sred[4][64];
  const bf16_t* Wh = W1p + (size_t)hop * NHID * 192;
  const float* b1h = b1 + hop * NHID;
  const float* w2h = W2 + hop * NHID;
  int tid = threadIdx.x;
  int r0 = blockIdx.x * 128;
  int lane = tid & 63, wv = tid >> 6;
  int wm = wv >> 1, wn = wv & 1;
  int quad = lane >> 4, l15 = lane & 15;

#pragma unroll
  for (int i = 0; i < 12; ++i) {
    int c = i * 256 + tid;
    int kc = c >> 7;
    int h = (c & 127) ^ ((kc & 3) << 2);
    GLOAD_LDS16(Wh + (size_t)h * 192 + kc * 8, Bs + (size_t)(i * 256 + wv * 64) * 8);
  }

  const bf16_t* arow[4];
#pragma unroll
  for (int mi = 0; mi < 4; ++mi) {
    int R = r0 + wm * 64 + mi * 16 + l15;
    arow[mi] = XT + (size_t)(R >> 5) * NBW + (size_t)(R & 31) * NW + quad * 8;
  }

  floatx4 zero4 = {0.f, 0.f, 0.f, 0.f};
  floatx4 acc[4][4];
#pragma unroll
  for (int mi = 0; mi < 4; ++mi)
#pragma unroll
    for (int ni = 0; ni < 4; ++ni) acc[mi][ni] = zero4;

  __syncthreads();

#pragma unroll
  for (int kb = 0; kb < 192; kb += 32) {
    int kc = (kb >> 3) + quad;
    bf16x8 af[4], bf[4];
#pragma unroll
    for (int mi = 0; mi < 4; ++mi)
      af[mi] = *(const bf16x8*)(arow[mi] + kb);  // k>=168 garbage; W1p pad=0
#pragma unroll
    for (int ni = 0; ni < 4; ++ni) {
      int hpos = (wn * 64 + ni * 16 + l15) ^ ((kc & 3) << 2);
      bf[ni] = *(const bf16x8*)(Bs + (size_t)(kc * 128 + hpos) * 8);
    }
#pragma unroll
    for (int mi = 0; mi < 4; ++mi)
#pragma unroll
      for (int ni = 0; ni < 4; ++ni)
        acc[mi][ni] = __builtin_amdgcn_mfma_f32_16x16x32_bf16(af[mi], bf[ni], acc[mi][ni], 0, 0, 0);
  }

  float part[4][4];
#pragma unroll
  for (int mi = 0; mi < 4; ++mi)
#pragma unroll
    for (int r = 0; r < 4; ++r) part[mi][r] = 0.f;
#pragma unroll
  for (int ni = 0; ni < 4; ++ni) {
    int col = wn * 64 + ni * 16 + l15;
    float b1v = b1h[col];
    float w2v = w2h[col];
#pragma unroll
    for (int mi = 0; mi < 4; ++mi)
#pragma unroll
      for (int r = 0; r < 4; ++r) {
        float h = acc[mi][ni][r] + b1v;
        h = h > 0.f ? h : 0.f;
        part[mi][r] += h * w2v;
      }
  }
#pragma unroll
  for (int off = 1; off < 16; off <<= 1)
#pragma unroll
    for (int mi = 0; mi < 4; ++mi)
#pragma unroll
      for (int r = 0; r < 4; ++r) part[mi][r] += __shfl_xor(part[mi][r], off);
  if (l15 == 0) {
#pragma unroll
    for (int mi = 0; mi < 4; ++mi)
#pragma unroll
      for (int r = 0; r < 4; ++r) sred[wv][mi * 16 + quad * 4 + r] = part[mi][r];
  }
  __syncthreads();
  if (tid < 128) {
    int half = tid >> 6;
    int lr = tid & 63;
    float v = sred[half * 2][lr] + sred[half * 2 + 1][lr] + b2[hop];
    int R = r0 + half * 64 + lr;
    int idx = (R & 31) * NM + (R >> 5);  // out[b*M + m]
    if (accumulate)
      out[idx] += v;
    else
      out[idx] = v;
  }
}

extern "C" void kernel_launch(void* const* d_in, const int* in_sizes, int n_in,
                              void* d_out, int out_size, void* d_ws, size_t ws_size,
                              hipStream_t stream) {
  const float* x = (const float*)d_in[0];
  const float* L = (const float*)d_in[1];
  const float* W1 = (const float*)d_in[2];
  const float* b1 = (const float*)d_in[3];
  const float* W2 = (const float*)d_in[4];
  const float* b2 = (const float*)d_in[5];
  float* out = (float*)d_out;

  char* ws = (char*)d_ws;
  size_t off = 0;
  auto walloc = [&](size_t bytes) -> void* {
    off = (off + 255) & ~(size_t)255;
    void* p = ws + off;
    off += bytes;
    return p;
  };
  const size_t SZ_T = (size_t)NBW * NM * 2;  // 22 MB
  bf16_t* W1p = (bf16_t*)walloc((size_t)7 * NHID * 192 * 2);
  bf16_t* Lb = (bf16_t*)walloc((size_t)NM * NM * 2);
  bf16_t* Xb = (bf16_t*)walloc(SZ_T);
  bf16_t* Tta = (bf16_t*)walloc(SZ_T);
  bf16_t* Ttb = (bf16_t*)walloc(SZ_T);
  bf16_t* XTa = (bf16_t*)walloc(SZ_T);
  bf16_t* XTb = (bf16_t*)walloc(SZ_T);
  bf16_t* Zt = (bf16_t*)walloc((size_t)4096 * NM * 2);  // 16.8 MB
  walloc(4096);  // guard for small A-pad overreads
  (void)ws_size; (void)in_sizes; (void)n_in; (void)out_size;

  prep_all<<<dim3(3207), dim3(256), 0, stream>>>(x, Xb, XTa, L, Lb, W1, W1p);

  // hop 0 on XT0 = XTa (stores out)
  mlp_score<<<dim3(512), dim3(256), 0, stream>>>(XTa, W1p, b1, W2, b2, out, 0, 0);

  // hops 1..5: T_i = T_{i-1} L^T; XT alternates b,a,b,a,b
  gemm_bk64<<<dim3(672), dim3(256), 0, stream>>>(Xb, Lb, Tta, XTb, 1);
  mlp_score<<<dim3(512), dim3(256), 0, stream>>>(XTb, W1p, b1, W2, b2, out, 1, 1);
  gemm_bk64<<<dim3(672), dim3(256), 0, stream>>>(Tta, Lb, Ttb, XTa, 1);
  mlp_score<<<dim3(512), dim3(256), 0, stream>>>(XTa, W1p, b1, W2, b2, out, 2, 1);
  gemm_bk64<<<dim3(672), dim3(256), 0, stream>>>(Ttb, Lb, Tta, XTb, 1);
  mlp_score<<<dim3(512), dim3(256), 0, stream>>>(XTb, W1p, b1, W2, b2, out, 3, 1);
  gemm_bk64<<<dim3(672), dim3(256), 0, stream>>>(Tta, Lb, Ttb, XTa, 1);
  mlp_score<<<dim3(512), dim3(256), 0, stream>>>(XTa, W1p, b1, W2, b2, out, 4, 1);
  gemm_bk64<<<dim3(672), dim3(256), 0, stream>>>(Ttb, Lb, nullptr, XTb, 0);
  mlp_score<<<dim3(512), dim3(256), 0, stream>>>(XTb, W1p, b1, W2, b2, out, 5, 1);

  // hop 6 via projection: Z = W1_6 * T5 (per b), then H6 = L * Z^T with fused score
  zproj<<<dim3(512), dim3(256), 0, stream>>>(XTb, W1p, Zt);
  gemm_h6<<<dim3(512), dim3(256), 0, stream>>>(Lb, Zt, b1, W2, b2, out);
}

// Round 7
// 554.967 us; speedup vs baseline: 1.2800x; 1.2800x over previous
//
#include <hip/hip_runtime.h>
#include <cstdint>
#include <cstddef>

typedef __bf16 bf16_t;
typedef __attribute__((ext_vector_type(8))) __bf16 bf16x8;
typedef __attribute__((ext_vector_type(4))) __bf16 bf16x4;
typedef __attribute__((ext_vector_type(4))) float floatx4;

#define NB 32
#define NW 168
#define NM 2048
#define NHID 128
#define NBW 5376  // NB*NW

#define GLOAD_LDS16(g, l)                                          \
  __builtin_amdgcn_global_load_lds(                                \
      (const __attribute__((address_space(1))) void*)(g),          \
      (__attribute__((address_space(3))) void*)(l), 16, 0, 0)

// One-shot prep: blocks [0,2688): x -> Xb [(b,w)][m] bf16 + XT [m][(b,w)] bf16;
// [2688,3200): L -> Lb bf16; [3200,3207): W1 -> W1p [7][128][192] bf16, k>=168 zeroed.
__global__ void prep_all(const float* __restrict__ x, bf16_t* __restrict__ Xb,
                         bf16_t* __restrict__ XT, const float* __restrict__ L,
                         bf16_t* __restrict__ Lb, const float* __restrict__ W1,
                         bf16_t* __restrict__ W1p) {
  __shared__ float tile[64][65];
  int bid = blockIdx.x;
  int t = threadIdx.x;
  if (bid < 2688) {
    const int C = NM;
    int r0 = (bid >> 5) * 64, c0 = (bid & 31) * 64;
    int tr = t >> 4, tc4 = (t & 15) * 4;
#pragma unroll
    for (int p = 0; p < 4; ++p) {
      int row = p * 16 + tr;
      float4 v = *(const float4*)(x + (size_t)(r0 + row) * C + c0 + tc4);
      tile[row][tc4 + 0] = v.x;
      tile[row][tc4 + 1] = v.y;
      tile[row][tc4 + 2] = v.z;
      tile[row][tc4 + 3] = v.w;
      bf16x4 o = {(bf16_t)v.x, (bf16_t)v.y, (bf16_t)v.z, (bf16_t)v.w};
      *(bf16x4*)(Xb + (size_t)(r0 + row) * C + c0 + tc4) = o;
    }
    __syncthreads();
#pragma unroll
    for (int p = 0; p < 4; ++p) {
      int c = p * 16 + tr;
      bf16x4 o = {(bf16_t)tile[tc4 + 0][c], (bf16_t)tile[tc4 + 1][c],
                  (bf16_t)tile[tc4 + 2][c], (bf16_t)tile[tc4 + 3][c]};
      *(bf16x4*)(XT + (size_t)(c0 + c) * NBW + r0 + tc4) = o;
    }
  } else if (bid < 3200) {
    int i = (bid - 2688) * 256 + t;
    const int n4 = NM * NM / 4;
    const int stride = 512 * 256;
    for (; i < n4; i += stride) {
      float4 v = ((const float4*)L)[i];
      bf16x4 o = {(bf16_t)v.x, (bf16_t)v.y, (bf16_t)v.z, (bf16_t)v.w};
      ((bf16x4*)Lb)[i] = o;
    }
  } else {
    int hop = bid - 3200;
    const float* src = W1 + (size_t)hop * NHID * NW;
    bf16_t* dst = W1p + (size_t)hop * NHID * 192;
    for (int c = t; c < 3072; c += 256) {
      int h = c / 24, kc = c % 24;
      bf16x8 o;
      if (kc < 21) {
        const float* s = src + (size_t)h * NW + kc * 8;
#pragma unroll
        for (int j = 0; j < 8; ++j) o[j] = (bf16_t)s[j];
      } else {
#pragma unroll
        for (int j = 0; j < 8; ++j) o[j] = (bf16_t)0.0f;
      }
      *(bf16x8*)(dst + (size_t)h * 192 + kc * 8) = o;
    }
  }
}

// Main NT GEMM, BK=32 (the measured-optimal m97 structure — do not tweak):
// Tt_out[(bw)][m] = sum_k A[(bw)][k]*Lb[m][k]. 672 blocks, LDS 2x8KB, XOR
// swizzle on the global source side, fragment reads 2-way (free).
// Always writes XTout (transposed, bf16x4-contig); Tt (row-major) if write_c.
__global__ void gemm_nt(const bf16_t* __restrict__ A, const bf16_t* __restrict__ Lb,
                        bf16_t* __restrict__ Tt, bf16_t* __restrict__ XTout, int write_c) {
  __shared__ bf16_t As[128 * 32];
  __shared__ bf16_t Bs[128 * 32];
  int tid = threadIdx.x, bid = blockIdx.x;
  int m0 = (bid >> 4) * 128, n0 = (bid & 15) * 128;
  int lane = tid & 63, wv = tid >> 6;
  int wm = wv >> 1, wn = wv & 1;
  int quad = lane >> 4, l15 = lane & 15;

  int p0 = wv * 128 + lane;
  int p1 = p0 + 64;
  int row0 = p0 >> 2, kc0 = (p0 & 3) ^ ((p0 >> 3) & 3);
  int row1 = p1 >> 2, kc1 = (p1 & 3) ^ ((p1 >> 3) & 3);
  const bf16_t* a0p = A + (size_t)(m0 + row0) * NM + kc0 * 8;
  const bf16_t* a1p = A + (size_t)(m0 + row1) * NM + kc1 * 8;
  const bf16_t* b0p = Lb + (size_t)(n0 + row0) * NM + kc0 * 8;
  const bf16_t* b1p = Lb + (size_t)(n0 + row1) * NM + kc1 * 8;
  bf16_t* As_d0 = As + (size_t)(wv * 128) * 8;
  bf16_t* As_d1 = As + (size_t)(wv * 128 + 64) * 8;
  bf16_t* Bs_d0 = Bs + (size_t)(wv * 128) * 8;
  bf16_t* Bs_d1 = Bs + (size_t)(wv * 128 + 64) * 8;
  int swz = (l15 >> 1) & 3;
  int kpos = (quad ^ swz) * 8;

  floatx4 zero4 = {0.f, 0.f, 0.f, 0.f};
  floatx4 acc[4][4];
#pragma unroll
  for (int mi = 0; mi < 4; ++mi)
#pragma unroll
    for (int ni = 0; ni < 4; ++ni) acc[mi][ni] = zero4;

  for (int kb = 0; kb < 2048; kb += 32) {
    GLOAD_LDS16(a0p + kb, As_d0);
    GLOAD_LDS16(a1p + kb, As_d1);
    GLOAD_LDS16(b0p + kb, Bs_d0);
    GLOAD_LDS16(b1p + kb, Bs_d1);
    __syncthreads();
    bf16x8 af[4], bf[4];
#pragma unroll
    for (int mi = 0; mi < 4; ++mi)
      af[mi] = *(const bf16x8*)(As + (wm * 64 + mi * 16 + l15) * 32 + kpos);
#pragma unroll
    for (int ni = 0; ni < 4; ++ni)
      bf[ni] = *(const bf16x8*)(Bs + (wn * 64 + ni * 16 + l15) * 32 + kpos);
#pragma unroll
    for (int mi = 0; mi < 4; ++mi)
#pragma unroll
      for (int ni = 0; ni < 4; ++ni)
        acc[mi][ni] = __builtin_amdgcn_mfma_f32_16x16x32_bf16(af[mi], bf[ni], acc[mi][ni], 0, 0, 0);
    __syncthreads();
  }
#pragma unroll
  for (int mi = 0; mi < 4; ++mi) {
#pragma unroll
    for (int ni = 0; ni < 4; ++ni) {
      int col = n0 + wn * 64 + ni * 16 + l15;
      int rowb = m0 + wm * 64 + mi * 16 + quad * 4;
      bf16x4 tv;
#pragma unroll
      for (int r = 0; r < 4; ++r) tv[r] = (bf16_t)acc[mi][ni][r];
      *(bf16x4*)(XTout + (size_t)col * NBW + rowb) = tv;
      if (write_c) {
#pragma unroll
        for (int r = 0; r < 4; ++r) Tt[(size_t)(rowb + r) * NM + col] = tv[r];
      }
    }
  }
}

// Hop-6 projection: Zt[(b*128+h)][k=m5] = sum_w W1p6[h][w] * XT5[m5][b*168+w].
// 512 blocks (b*16 + m5-tile); operands direct from global; tiny (2.8 GF).
__global__ void zproj(const bf16_t* __restrict__ XT5, const bf16_t* __restrict__ W1p,
                      bf16_t* __restrict__ Zt) {
  int bid = blockIdx.x;
  int b = bid >> 4, n0 = (bid & 15) * 128;
  const bf16_t* W6 = W1p + (size_t)6 * NHID * 192;
  int tid = threadIdx.x;
  int lane = tid & 63, wv = tid >> 6;
  int wm = wv >> 1, wn = wv & 1;
  int quad = lane >> 4, l15 = lane & 15;
  const bf16_t* arow[4];
  const bf16_t* brow[4];
#pragma unroll
  for (int mi = 0; mi < 4; ++mi)
    arow[mi] = W6 + (size_t)(wm * 64 + mi * 16 + l15) * 192 + quad * 8;
#pragma unroll
  for (int ni = 0; ni < 4; ++ni)
    brow[ni] = XT5 + (size_t)(n0 + wn * 64 + ni * 16 + l15) * NBW + b * NW + quad * 8;

  floatx4 zero4 = {0.f, 0.f, 0.f, 0.f};
  floatx4 acc[4][4];
#pragma unroll
  for (int mi = 0; mi < 4; ++mi)
#pragma unroll
    for (int ni = 0; ni < 4; ++ni) acc[mi][ni] = zero4;

#pragma unroll
  for (int kb = 0; kb < 192; kb += 32) {
    bf16x8 af[4], bf[4];
#pragma unroll
    for (int mi = 0; mi < 4; ++mi) af[mi] = *(const bf16x8*)(arow[mi] + kb);
#pragma unroll
    for (int ni = 0; ni < 4; ++ni) bf[ni] = *(const bf16x8*)(brow[ni] + kb);  // w>=168: A pad=0
#pragma unroll
    for (int mi = 0; mi < 4; ++mi)
#pragma unroll
      for (int ni = 0; ni < 4; ++ni)
        acc[mi][ni] = __builtin_amdgcn_mfma_f32_16x16x32_bf16(af[mi], bf[ni], acc[mi][ni], 0, 0, 0);
  }
#pragma unroll
  for (int mi = 0; mi < 4; ++mi) {
#pragma unroll
    for (int ni = 0; ni < 4; ++ni) {
      int col = n0 + wn * 64 + ni * 16 + l15;
      int rowb = b * 128 + wm * 64 + mi * 16 + quad * 4;
#pragma unroll
      for (int r = 0; r < 4; ++r)
        Zt[(size_t)(rowb + r) * NM + col] = (bf16_t)acc[mi][ni][r];
    }
  }
}

// Hop-6 GEMM (BK=32 m97 structure) + fused score:
// H[m][(b,h)] = sum_k Lb[m][k]*Zt[(b*128+h)][k];
// out[b*NM+m] += sum_h relu(H+b1_6)*W2_6 + b2_6. 512 blocks (m-tile*32 + n-tile).
__global__ void gemm_h6(const bf16_t* __restrict__ Lb, const bf16_t* __restrict__ Zt,
                        const float* __restrict__ b1, const float* __restrict__ W2,
                        const float* __restrict__ b2, float* __restrict__ out) {
  __shared__ bf16_t As[128 * 32];
  __shared__ bf16_t Bs[128 * 32];
  __shared__ float sred[4][64];
  int tid = threadIdx.x, bid = blockIdx.x;
  int m0 = (bid >> 5) * 128;
  int b = bid & 31;
  int n0 = b * 128;
  int lane = tid & 63, wv = tid >> 6;
  int wm = wv >> 1, wn = wv & 1;
  int quad = lane >> 4, l15 = lane & 15;

  int p0 = wv * 128 + lane;
  int p1 = p0 + 64;
  int row0 = p0 >> 2, kc0 = (p0 & 3) ^ ((p0 >> 3) & 3);
  int row1 = p1 >> 2, kc1 = (p1 & 3) ^ ((p1 >> 3) & 3);
  const bf16_t* a0p = Lb + (size_t)(m0 + row0) * NM + kc0 * 8;
  const bf16_t* a1p = Lb + (size_t)(m0 + row1) * NM + kc1 * 8;
  const bf16_t* b0p = Zt + (size_t)(n0 + row0) * NM + kc0 * 8;
  const bf16_t* b1p = Zt + (size_t)(n0 + row1) * NM + kc1 * 8;
  bf16_t* As_d0 = As + (size_t)(wv * 128) * 8;
  bf16_t* As_d1 = As + (size_t)(wv * 128 + 64) * 8;
  bf16_t* Bs_d0 = Bs + (size_t)(wv * 128) * 8;
  bf16_t* Bs_d1 = Bs + (size_t)(wv * 128 + 64) * 8;
  int swz = (l15 >> 1) & 3;
  int kpos = (quad ^ swz) * 8;

  floatx4 zero4 = {0.f, 0.f, 0.f, 0.f};
  floatx4 acc[4][4];
#pragma unroll
  for (int mi = 0; mi < 4; ++mi)
#pragma unroll
    for (int ni = 0; ni < 4; ++ni) acc[mi][ni] = zero4;

  for (int kb = 0; kb < 2048; kb += 32) {
    GLOAD_LDS16(a0p + kb, As_d0);
    GLOAD_LDS16(a1p + kb, As_d1);
    GLOAD_LDS16(b0p + kb, Bs_d0);
    GLOAD_LDS16(b1p + kb, Bs_d1);
    __syncthreads();
    bf16x8 af[4], bf[4];
#pragma unroll
    for (int mi = 0; mi < 4; ++mi)
      af[mi] = *(const bf16x8*)(As + (wm * 64 + mi * 16 + l15) * 32 + kpos);
#pragma unroll
    for (int ni = 0; ni < 4; ++ni)
      bf[ni] = *(const bf16x8*)(Bs + (wn * 64 + ni * 16 + l15) * 32 + kpos);
#pragma unroll
    for (int mi = 0; mi < 4; ++mi)
#pragma unroll
      for (int ni = 0; ni < 4; ++ni)
        acc[mi][ni] = __builtin_amdgcn_mfma_f32_16x16x32_bf16(af[mi], bf[ni], acc[mi][ni], 0, 0, 0);
    __syncthreads();
  }

  // fused epilogue: per output row m, sum_h relu(acc + b1_6[h]) * W2_6[h]
  const float* b1h = b1 + 6 * NHID;
  const float* w2h = W2 + 6 * NHID;
  float part[4][4];
#pragma unroll
  for (int mi = 0; mi < 4; ++mi)
#pragma unroll
    for (int r = 0; r < 4; ++r) part[mi][r] = 0.f;
#pragma unroll
  for (int ni = 0; ni < 4; ++ni) {
    int h = wn * 64 + ni * 16 + l15;
    float b1v = b1h[h];
    float w2v = w2h[h];
#pragma unroll
    for (int mi = 0; mi < 4; ++mi)
#pragma unroll
      for (int r = 0; r < 4; ++r) {
        float hh = acc[mi][ni][r] + b1v;
        hh = hh > 0.f ? hh : 0.f;
        part[mi][r] += hh * w2v;
      }
  }
#pragma unroll
  for (int off = 1; off < 16; off <<= 1)
#pragma unroll
    for (int mi = 0; mi < 4; ++mi)
#pragma unroll
      for (int r = 0; r < 4; ++r) part[mi][r] += __shfl_xor(part[mi][r], off);
  if (l15 == 0) {
#pragma unroll
    for (int mi = 0; mi < 4; ++mi)
#pragma unroll
      for (int r = 0; r < 4; ++r) sred[wv][mi * 16 + quad * 4 + r] = part[mi][r];
  }
  __syncthreads();
  if (tid < 128) {
    int half = tid >> 6;
    int lr = tid & 63;
    float v = sred[half * 2][lr] + sred[half * 2 + 1][lr] + b2[6];
    out[(size_t)b * NM + m0 + half * 64 + lr] += v;  // unique (b,m) per block
  }
}

// Per-hop MLP + score (hops 0..5). Rows r = m*32+b (128/block); A from XT,
// W1 staged from zero-padded W1p into LDS [kc][h^swz].
__global__ void mlp_score(const bf16_t* __restrict__ XT, const bf16_t* __restrict__ W1p,
                          const float* __restrict__ b1, const float* __restrict__ W2,
                          const float* __restrict__ b2, float* __restrict__ out,
                          int hop, int accumulate) {
  __shared__ bf16_t Bs[24 * 128 * 8];  // 48 KB
  __shared__ float sred[4][64];
  const bf16_t* Wh = W1p + (size_t)hop * NHID * 192;
  const float* b1h = b1 + hop * NHID;
  const float* w2h = W2 + hop * NHID;
  int tid = threadIdx.x;
  int r0 = blockIdx.x * 128;
  int lane = tid & 63, wv = tid >> 6;
  int wm = wv >> 1, wn = wv & 1;
  int quad = lane >> 4, l15 = lane & 15;

#pragma unroll
  for (int i = 0; i < 12; ++i) {
    int c = i * 256 + tid;
    int kc = c >> 7;
    int h = (c & 127) ^ ((kc & 3) << 2);
    GLOAD_LDS16(Wh + (size_t)h * 192 + kc * 8, Bs + (size_t)(i * 256 + wv * 64) * 8);
  }

  const bf16_t* arow[4];
#pragma unroll
  for (int mi = 0; mi < 4; ++mi) {
    int R = r0 + wm * 64 + mi * 16 + l15;
    arow[mi] = XT + (size_t)(R >> 5) * NBW + (size_t)(R & 31) * NW + quad * 8;
  }

  floatx4 zero4 = {0.f, 0.f, 0.f, 0.f};
  floatx4 acc[4][4];
#pragma unroll
  for (int mi = 0; mi < 4; ++mi)
#pragma unroll
    for (int ni = 0; ni < 4; ++ni) acc[mi][ni] = zero4;

  __syncthreads();

#pragma unroll
  for (int kb = 0; kb < 192; kb += 32) {
    int kc = (kb >> 3) + quad;
    bf16x8 af[4], bf[4];
#pragma unroll
    for (int mi = 0; mi < 4; ++mi)
      af[mi] = *(const bf16x8*)(arow[mi] + kb);  // k>=168 garbage; W1p pad=0
#pragma unroll
    for (int ni = 0; ni < 4; ++ni) {
      int hpos = (wn * 64 + ni * 16 + l15) ^ ((kc & 3) << 2);
      bf[ni] = *(const bf16x8*)(Bs + (size_t)(kc * 128 + hpos) * 8);
    }
#pragma unroll
    for (int mi = 0; mi < 4; ++mi)
#pragma unroll
      for (int ni = 0; ni < 4; ++ni)
        acc[mi][ni] = __builtin_amdgcn_mfma_f32_16x16x32_bf16(af[mi], bf[ni], acc[mi][ni], 0, 0, 0);
  }

  float part[4][4];
#pragma unroll
  for (int mi = 0; mi < 4; ++mi)
#pragma unroll
    for (int r = 0; r < 4; ++r) part[mi][r] = 0.f;
#pragma unroll
  for (int ni = 0; ni < 4; ++ni) {
    int col = wn * 64 + ni * 16 + l15;
    float b1v = b1h[col];
    float w2v = w2h[col];
#pragma unroll
    for (int mi = 0; mi < 4; ++mi)
#pragma unroll
      for (int r = 0; r < 4; ++r) {
        float h = acc[mi][ni][r] + b1v;
        h = h > 0.f ? h : 0.f;
        part[mi][r] += h * w2v;
      }
  }
#pragma unroll
  for (int off = 1; off < 16; off <<= 1)
#pragma unroll
    for (int mi = 0; mi < 4; ++mi)
#pragma unroll
      for (int r = 0; r < 4; ++r) part[mi][r] += __shfl_xor(part[mi][r], off);
  if (l15 == 0) {
#pragma unroll
    for (int mi = 0; mi < 4; ++mi)
#pragma unroll
      for (int r = 0; r < 4; ++r) sred[wv][mi * 16 + quad * 4 + r] = part[mi][r];
  }
  __syncthreads();
  if (tid < 128) {
    int half = tid >> 6;
    int lr = tid & 63;
    float v = sred[half * 2][lr] + sred[half * 2 + 1][lr] + b2[hop];
    int R = r0 + half * 64 + lr;
    int idx = (R & 31) * NM + (R >> 5);  // out[b*M + m]
    if (accumulate)
      out[idx] += v;
    else
      out[idx] = v;
  }
}

extern "C" void kernel_launch(void* const* d_in, const int* in_sizes, int n_in,
                              void* d_out, int out_size, void* d_ws, size_t ws_size,
                              hipStream_t stream) {
  const float* x = (const float*)d_in[0];
  const float* L = (const float*)d_in[1];
  const float* W1 = (const float*)d_in[2];
  const float* b1 = (const float*)d_in[3];
  const float* W2 = (const float*)d_in[4];
  const float* b2 = (const float*)d_in[5];
  float* out = (float*)d_out;

  char* ws = (char*)d_ws;
  size_t off = 0;
  auto walloc = [&](size_t bytes) -> void* {
    off = (off + 255) & ~(size_t)255;
    void* p = ws + off;
    off += bytes;
    return p;
  };
  const size_t SZ_T = (size_t)NBW * NM * 2;  // 22 MB
  bf16_t* W1p = (bf16_t*)walloc((size_t)7 * NHID * 192 * 2);
  bf16_t* Lb = (bf16_t*)walloc((size_t)NM * NM * 2);
  bf16_t* Xb = (bf16_t*)walloc(SZ_T);
  bf16_t* Tta = (bf16_t*)walloc(SZ_T);
  bf16_t* Ttb = (bf16_t*)walloc(SZ_T);
  bf16_t* XTa = (bf16_t*)walloc(SZ_T);
  bf16_t* XTb = (bf16_t*)walloc(SZ_T);
  bf16_t* Zt = (bf16_t*)walloc((size_t)4096 * NM * 2);  // 16.8 MB
  walloc(4096);  // guard for small A/B pad overreads
  (void)ws_size; (void)in_sizes; (void)n_in; (void)out_size;

  prep_all<<<dim3(3207), dim3(256), 0, stream>>>(x, Xb, XTa, L, Lb, W1, W1p);

  // hop 0 on XT0 = XTa (stores out)
  mlp_score<<<dim3(512), dim3(256), 0, stream>>>(XTa, W1p, b1, W2, b2, out, 0, 0);

  // hops 1..5: T_i = T_{i-1} L^T; XT alternates b,a,b,a,b
  gemm_nt<<<dim3(672), dim3(256), 0, stream>>>(Xb, Lb, Tta, XTb, 1);
  mlp_score<<<dim3(512), dim3(256), 0, stream>>>(XTb, W1p, b1, W2, b2, out, 1, 1);
  gemm_nt<<<dim3(672), dim3(256), 0, stream>>>(Tta, Lb, Ttb, XTa, 1);
  mlp_score<<<dim3(512), dim3(256), 0, stream>>>(XTa, W1p, b1, W2, b2, out, 2, 1);
  gemm_nt<<<dim3(672), dim3(256), 0, stream>>>(Ttb, Lb, Tta, XTb, 1);
  mlp_score<<<dim3(512), dim3(256), 0, stream>>>(XTb, W1p, b1, W2, b2, out, 3, 1);
  gemm_nt<<<dim3(672), dim3(256), 0, stream>>>(Tta, Lb, Ttb, XTa, 1);
  mlp_score<<<dim3(512), dim3(256), 0, stream>>>(XTa, W1p, b1, W2, b2, out, 4, 1);
  gemm_nt<<<dim3(672), dim3(256), 0, stream>>>(Ttb, Lb, nullptr, XTb, 0);
  mlp_score<<<dim3(512), dim3(256), 0, stream>>>(XTb, W1p, b1, W2, b2, out, 5, 1);

  // hop 6 via projection: Z = W1_6 * T5 (per b), then H6 = L * Z^T, fused score
  zproj<<<dim3(512), dim3(256), 0, stream>>>(XTb, W1p, Zt);
  gemm_h6<<<dim3(512), dim3(256), 0, stream>>>(Lb, Zt, b1, W2, b2, out);
}